// Round 9
// baseline (75.005 us; speedup 1.0000x reference)
//
#include <hip/hip_runtime.h>
#include <math.h>

#define NB 16
#define TQ 2048
#define TK 2048
#define DD 128
#define DVV 128

constexpr int KTILE = 32;   // k rows per staged tile
constexpr int QTILE = 128;  // 4 waves x 32 q-rows

typedef __attribute__((ext_vector_type(8))) _Float16 half8;
typedef __attribute__((ext_vector_type(16))) float f32x16;
typedef __attribute__((ext_vector_type(4))) float f32x4;

__device__ inline float fast_exp2(float x) { return __builtin_amdgcn_exp2f(x); }
__device__ inline void setprio1() { __builtin_amdgcn_s_setprio(1); }
__device__ inline void setprio0() { __builtin_amdgcn_s_setprio(0); }

__device__ inline unsigned pk2(float a, float b) {
    auto h = __builtin_amdgcn_cvt_pkrtz(a, b);   // __fp16 ext_vector(2)
    unsigned u;
    __builtin_memcpy(&u, &h, 4);
    return u;
}

__device__ inline void glds16(const _Float16* g, _Float16* l) {
    __builtin_amdgcn_global_load_lds(
        (const __attribute__((address_space(1))) void*)g,
        (__attribute__((address_space(3))) void*)l, 16, 0, 0);
}

// ---- pre-pass: fp32 K/V -> fp16, packed in 32x32x16 MFMA fragment order ----
// K tile (A-op): half off = c*512 + lane*8 + j  <->  K[row=lane&31][c*16+(lane>>5)*8+j]
// V tile (A-op of V^T): off = (n*2+kc)*512 + lane*8 + j <-> V[kc*16+(lane>>5)*8+j][n*32+(lane&31)]
__global__ __launch_bounds__(256)
void repack(const float* __restrict__ kg, const float* __restrict__ vg,
            const int* __restrict__ vlg,
            _Float16* __restrict__ Kpk, _Float16* __restrict__ Vpk)
{
    const int bt = blockIdx.x;          // b*64 + t
    const int b = bt >> 6, t = bt & 63;
    if (t * KTILE >= vlg[b]) return;
    const int tid = threadIdx.x;

    __shared__ float Vlds[32][129];

    const float* kin = kg + ((size_t)b * TK + t * KTILE) * DD;
    _Float16* kout = Kpk + ((size_t)bt << 12);
#pragma unroll
    for (int pp = 0; pp < 2; ++pp) {
        int s = tid + pp * 256;
        int c = s >> 6, l = s & 63;
        int row = l & 31, d0 = c * 16 + (l >> 5) * 8;
        const float* ip = kin + row * DD + d0;
        float4 f0 = *(const float4*)ip;
        float4 f1 = *(const float4*)(ip + 4);
        half8 hh;
        hh[0] = (_Float16)f0.x; hh[1] = (_Float16)f0.y;
        hh[2] = (_Float16)f0.z; hh[3] = (_Float16)f0.w;
        hh[4] = (_Float16)f1.x; hh[5] = (_Float16)f1.y;
        hh[6] = (_Float16)f1.z; hh[7] = (_Float16)f1.w;
        *(half8*)(kout + (size_t)s * 8) = hh;
    }

    const float* vin = vg + ((size_t)b * TK + t * KTILE) * DVV;
#pragma unroll
    for (int pp = 0; pp < 4; ++pp) {
        int idx = tid + pp * 256;
        int r = idx >> 5, c4 = (idx & 31) * 4;
        float4 f = *(const float4*)(vin + r * DVV + c4);
        Vlds[r][c4 + 0] = f.x; Vlds[r][c4 + 1] = f.y;
        Vlds[r][c4 + 2] = f.z; Vlds[r][c4 + 3] = f.w;
    }
    __syncthreads();
    _Float16* vout = Vpk + ((size_t)bt << 12);
#pragma unroll
    for (int pp = 0; pp < 2; ++pp) {
        int s = tid + pp * 256;
        int sv = s >> 6, l = s & 63;
        int dv = (sv >> 1) * 32 + (l & 31);
        int k0 = (sv & 1) * 16 + (l >> 5) * 8;
        half8 hh;
#pragma unroll
        for (int j = 0; j < 8; ++j)
            hh[j] = (_Float16)Vlds[k0 + j][dv];
        *(half8*)(vout + (size_t)s * 8) = hh;
    }
}

// ---- attention: one (b, q-tile, split) per block; 4 waves; 32x32 MFMA ----
__global__ __launch_bounds__(256, 3)
void attn_fwd(const float* __restrict__ qg,
              const _Float16* __restrict__ Kpk, const _Float16* __restrict__ Vpk,
              const int* __restrict__ vlg,
              float* __restrict__ outg, _Float16* __restrict__ wso,
              float* __restrict__ wsml, int nsplit, int tpb)
{
    __shared__ __align__(16) _Float16 smem[16384];  // K0|K1|V0|V1, 4096 halfs each

    const int tid  = threadIdx.x;
    const int wid  = tid >> 6;        // 0..3
    const int lane = tid & 63;
    const int l31  = lane & 31;
    const int hi   = lane >> 5;       // 0/1

    const int b     = blockIdx.x & (NB - 1);
    const int qbase = (blockIdx.x >> 4) * QTILE;
    const int sp    = blockIdx.y;

    const int VL  = vlg[b];
    const int nkt = (VL + KTILE - 1) / KTILE;
    const int t0  = sp * tpb;
    const int t1  = min(nkt, t0 + tpb);
    if (t0 >= t1) return;             // inactive split: exit before any barrier

    const _Float16* ktb = Kpk + ((size_t)(b * 64) << 12);
    const _Float16* vtb = Vpk + ((size_t)(b * 64) << 12);

    // ---- Q B-fragments (col=q=l31, k=d-chunk), scale*log2e folded ----
    half8 qf[8];
    {
        const float scale = 0.08838834764831845f * 1.4426950408889634f;
        const float* qp = qg + (size_t)(b * TQ + qbase + wid * 32 + l31) * DD;
#pragma unroll
        for (int c = 0; c < 8; ++c) {
            int d0 = c * 16 + hi * 8;
            float4 f0 = *(const float4*)(qp + d0);
            float4 f1 = *(const float4*)(qp + d0 + 4);
            half8 tq;
            tq[0] = (_Float16)(f0.x * scale); tq[1] = (_Float16)(f0.y * scale);
            tq[2] = (_Float16)(f0.z * scale); tq[3] = (_Float16)(f0.w * scale);
            tq[4] = (_Float16)(f1.x * scale); tq[5] = (_Float16)(f1.y * scale);
            tq[6] = (_Float16)(f1.z * scale); tq[7] = (_Float16)(f1.w * scale);
            qf[c] = tq;
        }
    }

    // ---- DMA staging: waves 0,1 -> K halves; waves 2,3 -> V halves ----
    auto STAGE = [&](int buf, int t) {
        const bool isK = wid < 2;
        const int hf = wid & 1;
        const _Float16* src = (isK ? ktb : vtb) + ((size_t)t << 12) + hf * 2048 + lane * 8;
        _Float16* dst = smem + (isK ? 0 : 8192) + buf * 4096 + hf * 2048;
#pragma unroll
        for (int u = 0; u < 4; ++u)
            glds16(src + u * 512, dst + u * 512);
    };

    float m_i = -INFINITY, l_i = 0.f;
    f32x16 o[4];
#pragma unroll
    for (int n = 0; n < 4; ++n)
#pragma unroll
        for (int r = 0; r < 16; ++r) o[n][r] = 0.f;

    STAGE(0, t0);
    int cur = 0;
    for (int t = t0; t < t1; ++t) {
        const int kb = t * KTILE;
        const bool pre = (t + 1 < t1);
        if (pre) STAGE(cur ^ 1, t + 1);

        if (pre) asm volatile("s_waitcnt vmcnt(4)\ns_barrier" ::: "memory");
        else     asm volatile("s_waitcnt vmcnt(0)\ns_barrier" ::: "memory");

        const _Float16* kbuf = smem + cur * 4096;
        const _Float16* vbuf = smem + 8192 + cur * 4096;

        // ---- S^T = K Q^T (32k x 32q), acc over d=128 in 8 chunks ----
        f32x16 sc;
#pragma unroll
        for (int r = 0; r < 16; ++r) sc[r] = 0.f;
        setprio1();
#pragma unroll
        for (int c = 0; c < 8; ++c) {
            half8 kf = *(const half8*)(kbuf + c * 512 + lane * 8);
            sc = __builtin_amdgcn_mfma_f32_32x32x16_f16(kf, qf[c], sc, 0, 0, 0);
        }
        setprio0();

        // ---- mask k rows >= VL (boundary tile only) ----
        if (kb + KTILE > VL) {
#pragma unroll
            for (int r = 0; r < 16; ++r) {
                int rowk = kb + (r & 3) + 8 * (r >> 2) + 4 * hi;
                if (rowk >= VL) sc[r] = -1e30f;
            }
        }

        // ---- per-lane softmax (col q = l31): 16 in-lane + 1 cross ----
        float mx = sc[0];
#pragma unroll
        for (int r = 1; r < 16; ++r) mx = fmaxf(mx, sc[r]);
        mx = fmaxf(mx, __shfl_xor(mx, 32));

        const bool skip = __all(mx <= m_i + 8.0f);   // defer-max (log2 domain)
        const float mnew = skip ? m_i : fmaxf(m_i, mx);

        float p[16];
        float sum = 0.f;
#pragma unroll
        for (int r = 0; r < 16; ++r) {
            p[r] = fast_exp2(sc[r] - mnew);
            sum += p[r];
        }
        sum += __shfl_xor(sum, 32);

        // ---- P -> f16 B-fragments fully in-register (cvt_pk + xor32) ----
        unsigned a0 = pk2(p[0],  p[1]),  a1 = pk2(p[2],  p[3]);
        unsigned a2 = pk2(p[4],  p[5]),  a3 = pk2(p[6],  p[7]);
        unsigned b0 = pk2(p[8],  p[9]),  b1 = pk2(p[10], p[11]);
        unsigned b2 = pk2(p[12], p[13]), b3 = pk2(p[14], p[15]);
        unsigned pa0 = __shfl_xor(a0, 32), pa1 = __shfl_xor(a1, 32);
        unsigned pa2 = __shfl_xor(a2, 32), pa3 = __shfl_xor(a3, 32);
        unsigned pb0 = __shfl_xor(b0, 32), pb1 = __shfl_xor(b1, 32);
        unsigned pb2 = __shfl_xor(b2, 32), pb3 = __shfl_xor(b3, 32);
        union PF { unsigned u[4]; half8 v; } pf0, pf1;
        pf0.u[0] = hi ? pa2 : a0;  pf0.u[1] = hi ? pa3 : a1;
        pf0.u[2] = hi ? a2  : pa0; pf0.u[3] = hi ? a3  : pa1;
        pf1.u[0] = hi ? pb2 : b0;  pf1.u[1] = hi ? pb3 : b1;
        pf1.u[2] = hi ? b2  : pb0; pf1.u[3] = hi ? b3  : pb1;

        if (skip) {
            l_i += sum;
        } else {
            const float corr = fast_exp2(m_i - mnew);
            l_i = l_i * corr + sum;
            m_i = mnew;
#pragma unroll
            for (int n = 0; n < 4; ++n)
#pragma unroll
                for (int r = 0; r < 16; ++r) o[n][r] *= corr;
        }

        // ---- O^T += V^T P^T (4 d-quadrants x 2 k-chunks) ----
        setprio1();
#pragma unroll
        for (int n = 0; n < 4; ++n) {
            half8 v0 = *(const half8*)(vbuf + (n * 2 + 0) * 512 + lane * 8);
            o[n] = __builtin_amdgcn_mfma_f32_32x32x16_f16(v0, pf0.v, o[n], 0, 0, 0);
            half8 v1 = *(const half8*)(vbuf + (n * 2 + 1) * 512 + lane * 8);
            o[n] = __builtin_amdgcn_mfma_f32_32x32x16_f16(v1, pf1.v, o[n], 0, 0, 0);
        }
        setprio0();

        asm volatile("s_waitcnt lgkmcnt(0)\ns_barrier" ::: "memory");
        cur ^= 1;
    }

    // ---- epilogue: per-wave LDS transpose (reuse smem), coalesced stores ----
    const float inv = (nsplit == 1) ? (1.0f / l_i) : 1.0f;  // stats are lane-local
    float* tp = (float*)smem + wid * 1056;                  // 32 x 33 f32 patch
#pragma unroll
    for (int n = 0; n < 4; ++n) {
#pragma unroll
        for (int r = 0; r < 16; ++r) {
            int row = (r & 3) + 8 * (r >> 2) + 4 * hi;      // d within quadrant
            tp[l31 * 33 + row] = o[n][r] * inv;             // tp[q][d]
        }
        asm volatile("s_waitcnt lgkmcnt(0)" ::: "memory");
        if (nsplit == 1) {
            float* op = outg + (size_t)(b * TQ + qbase + wid * 32) * DVV + n * 32 + l31;
#pragma unroll
            for (int rr = 0; rr < 16; ++rr) {
                int qq = rr * 2 + hi;
                op[(size_t)qq * DVV] = tp[qq * 33 + l31];
            }
        } else {
            _Float16* po = wso + ((size_t)(sp * NB + b) * TQ + qbase + wid * 32) * DVV
                           + n * 32 + l31;
#pragma unroll
            for (int rr = 0; rr < 16; ++rr) {
                int qq = rr * 2 + hi;
                po[(size_t)qq * DVV] = (_Float16)tp[qq * 33 + l31];
            }
        }
        asm volatile("s_waitcnt lgkmcnt(0)" ::: "memory");
    }
    if (nsplit > 1 && hi == 0) {
        int q = qbase + wid * 32 + l31;
        *(float2*)&wsml[((size_t)(sp * NB + b) * TQ + q) * 2] = make_float2(m_i, l_i);
    }
}

// ---- combine pass: softmax-weighted merge of splits ----
__global__ __launch_bounds__(256)
void attn_combine(const _Float16* __restrict__ wso, const float* __restrict__ wsml,
                  const int* __restrict__ vlg, float* __restrict__ outg, int tpb)
{
    const int idx = blockIdx.x * 256 + threadIdx.x;   // NB*TQ*16, 8 elems/thread
    const int d8 = idx & 15;
    const int q  = (idx >> 4) & (TQ - 1);
    const int b  = idx >> 15;

    const int VL  = vlg[b];
    const int nkt = (VL + KTILE - 1) / KTILE;
    const int nv  = (nkt + tpb - 1) / tpb;            // active splits

    float M = -1e30f, den = 0.f;
    float acc[8] = {0.f, 0.f, 0.f, 0.f, 0.f, 0.f, 0.f, 0.f};
    for (int s = 0; s < nv; ++s) {
        const size_t row = (size_t)(s * NB + b) * TQ + q;
        float2 ml = *(const float2*)&wsml[row * 2];
        float Mn = fmaxf(M, ml.x);
        float c  = fast_exp2(M - Mn);
        float w  = fast_exp2(ml.x - Mn);
        half8 ov = *(const half8*)&wso[row * DVV + d8 * 8];
#pragma unroll
        for (int j = 0; j < 8; ++j)
            acc[j] = acc[j] * c + (float)ov[j] * w;
        den = den * c + w * ml.y;
        M = Mn;
    }
    const float inv = 1.0f / den;
    float* op = outg + ((size_t)b * TQ + q) * DVV + d8 * 8;
    f32x4 r0 = {acc[0] * inv, acc[1] * inv, acc[2] * inv, acc[3] * inv};
    f32x4 r1 = {acc[4] * inv, acc[5] * inv, acc[6] * inv, acc[7] * inv};
    *(f32x4*)op = r0;
    *(f32x4*)(op + 4) = r1;
}

extern "C" void kernel_launch(void* const* d_in, const int* in_sizes, int n_in,
                              void* d_out, int out_size, void* d_ws, size_t ws_size,
                              hipStream_t stream) {
    const float* q  = (const float*)d_in[0];
    const float* k  = (const float*)d_in[1];
    const float* v  = (const float*)d_in[2];
    const int*   vl = (const int*)d_in[3];
    float* out = (float*)d_out;

    const size_t pk_elems  = (size_t)NB * 64 * 4096;            // halfs per tensor
    const size_t pk_bytes  = 2 * pk_elems * sizeof(_Float16);   // K + V = 16.78 MB
    const size_t o_elems   = (size_t)NB * TQ * DVV;
    const size_t per_split = o_elems * sizeof(_Float16)
                           + (size_t)NB * TQ * 2 * sizeof(float);

    int ns = 1;
    if      (ws_size >= pk_bytes + 8 * per_split) ns = 8;
    else if (ws_size >= pk_bytes + 4 * per_split) ns = 4;
    else if (ws_size >= pk_bytes + 2 * per_split) ns = 2;
    const int tpb = 64 / ns;   // k-tiles per block (balanced splits)

    _Float16* Kpk = (_Float16*)d_ws;
    _Float16* Vpk = Kpk + pk_elems;
    _Float16* wso = Vpk + pk_elems;
    float*   wsml = (float*)(wso + (size_t)ns * o_elems);

    hipLaunchKernelGGL(repack, dim3(NB * 64), dim3(256), 0, stream,
                       k, v, vl, Kpk, Vpk);

    dim3 grid(NB * (TQ / QTILE), ns);
    hipLaunchKernelGGL(attn_fwd, grid, dim3(256), 0, stream,
                       q, Kpk, Vpk, vl, out, wso, wsml, ns, tpb);

    if (ns > 1) {
        dim3 cgrid((NB * TQ * 16) / 256);
        hipLaunchKernelGGL(attn_combine, cgrid, dim3(256), 0, stream,
                           wso, wsml, vl, out, tpb);
    }
}